// Round 13
// baseline (221.739 us; speedup 1.0000x reference)
//
#include <hip/hip_runtime.h>
#include <cstdint>
#include <cstddef>

#define B_   256
#define T_   14
#define INF_ 2048
#define H_   512
#define HW_  49
#define NG_  2048   /* 4*H */
#define KC_  1024   /* H (h) + H (c) */
#define NBLK 256

typedef __attribute__((ext_vector_type(8))) _Float16 f16x8;
typedef __attribute__((ext_vector_type(4))) float f32x4;
typedef _Float16 f16;
typedef unsigned long long u64;

typedef const void __attribute__((address_space(1))) gvoid_t;
typedef void __attribute__((address_space(3))) svoid_t;

__device__ __forceinline__ void async16(const void* g, void* l) {
  __builtin_amdgcn_global_load_lds((gvoid_t*)g, (svoid_t*)l, 16, 0, 0);
}

__device__ __forceinline__ float sigm(float x) { return 1.0f / (1.0f + __expf(-x)); }

// ---- agent-scope (L3-coherent) relaxed accessors ----
__device__ __forceinline__ float aload(const float* p) {
  return __hip_atomic_load(p, __ATOMIC_RELAXED, __HIP_MEMORY_SCOPE_AGENT);
}
__device__ __forceinline__ int aloadi(const int* p) {
  return __hip_atomic_load(p, __ATOMIC_RELAXED, __HIP_MEMORY_SCOPE_AGENT);
}
__device__ __forceinline__ u64 aload64(const void* p) {
  return __hip_atomic_load((const u64*)p, __ATOMIC_RELAXED, __HIP_MEMORY_SCOPE_AGENT);
}
__device__ __forceinline__ void astore(float* p, float v) {
  __hip_atomic_store(p, v, __ATOMIC_RELAXED, __HIP_MEMORY_SCOPE_AGENT);
}
__device__ __forceinline__ void astore64(void* p, u64 v) {
  __hip_atomic_store((u64*)p, v, __ATOMIC_RELAXED, __HIP_MEMORY_SCOPE_AGENT);
}
__device__ __forceinline__ void astorei(int* p, int v) {
  __hip_atomic_store(p, v, __ATOMIC_RELAXED, __HIP_MEMORY_SCOPE_AGENT);
}

// slot barrier (final-only): producer stamps own slot; consumers poll 32 slots
__device__ __forceinline__ void waitSlots(const int* slots, const int target) {
  const int* p = slots + (threadIdx.x & 31);
  for (;;) {
    const int v = aloadi(p);
    if (__all(v >= target)) break;
    __builtin_amdgcn_s_sleep(1);
  }
}

// ---------------- fused prep (weight conversion) + gather ----------------
__global__ __launch_bounds__(256) void k_prep_gather(
    const float* __restrict__ Wx, const float* __restrict__ bx,
    const float* __restrict__ Wh, const float* __restrict__ Wc,
    const float* __restrict__ bh, const float* __restrict__ bc,
    const int* __restrict__ fix, const float* __restrict__ x,
    f16* __restrict__ Wxh, float* __restrict__ bxp,
    f16* __restrict__ Wbig, f16* __restrict__ Wc2h,
    float* __restrict__ biasb, f16* __restrict__ xg, int* __restrict__ tlast)
{
  const int bid = blockIdx.x;
  const int tid = threadIdx.x;
  if (bid < 1024) {
    __shared__ float rows[256 * 49];
    __shared__ int wv[T_];
    __shared__ int anyS;
    const int b = bid >> 2, part = bid & 3;
    int a = 0;
    for (int i = tid; i < B_ * T_; i += 256) a |= fix[2 * i + 1];
    if (tid == 0) anyS = 0;
    __syncthreads();
    if (a) anyS = 1;
    __syncthreads();
    const int is64 = (anyS == 0);
    if (tid < T_) wv[tid] = is64 ? fix[2 * (b * T_ + tid)] : fix[b * T_ + tid];
    __syncthreads();
    if (part == 0 && tid == 0) {
      int cnt = 0;
      for (int t = 0; t < T_; ++t) cnt += (wv[t] == 0);
      tlast[b] = (cnt < T_) ? (T_ - 1 - cnt) : (T_ - 1);
    }
    const float* xb = x + (size_t)b * (INF_ * HW_);
    for (int c = 0; c < 2; ++c) {
      const int ch = part * 2 + c;
      if (c) __syncthreads();
      const float4* src = (const float4*)(xb + (size_t)ch * 256 * 49);
      float4* dst4 = (float4*)rows;
      for (int i = tid; i < 3136; i += 256) dst4[i] = src[i];
      __syncthreads();
#pragma unroll
      for (int t = 0; t < T_; ++t)
        xg[(size_t)(b * T_ + t) * INF_ + ch * 256 + tid] = (f16)rows[tid * 49 + wv[t]];
    }
  } else {
    const int tid2 = (bid - 1024) * 256 + tid;
    const int nth = 512 * 256;
    for (int i = tid2; i < 4 * H_ * INF_; i += nth) {
      const int n = i >> 11, k = i & 2047;
      const int g = n & 3, h = n >> 2;
      Wxh[i] = (f16)Wx[((size_t)(g * H_ + h)) * INF_ + k];
    }
    for (int i = tid2; i < NG_ * KC_; i += nth) {
      const int n = i >> 10, k = i & 1023;
      const int g = n & 3, h = n >> 2;
      float v;
      if (k < H_) v = Wh[((size_t)(g * H_ + h)) * H_ + k];
      else {
        const int kk = k - H_;
        v = (g == 0) ? Wc[h * H_ + kk] : (g == 1) ? Wc[H_ * H_ + h * H_ + kk] : 0.0f;
      }
      Wbig[i] = (f16)v;
    }
    for (int i = tid2; i < H_ * H_; i += nth) Wc2h[i] = (f16)Wc[2 * H_ * H_ + i];
    for (int i = tid2; i < NG_; i += nth) {
      const int g = i & 3, h = i >> 2;
      biasb[i] = bh[g * H_ + h] + ((g == 0) ? bc[h] : (g == 1) ? bc[H_ + h] : 0.0f);
      bxp[i] = bx[g * H_ + h];
    }
  }
}

// ---------------- big GEMM: xproj[3584][2048] = xg @ Wxh^T + bxp ----------------
__global__ __launch_bounds__(256) void k_gemm_big(
    const f16* __restrict__ A, const f16* __restrict__ Bw,
    const float* __restrict__ bxp, float* __restrict__ Cproj)
{
  __shared__ alignas(16) f16 As[128 * 64];
  __shared__ alignas(16) f16 Bs[128 * 64];
  const int tid = threadIdx.x;
  const int lane = tid & 63;
  const int w = tid >> 6;
  const int wm = w >> 1, wn = w & 1;
  const int flat = blockIdx.y * 16 + blockIdx.x;
  const int wg = (flat & 7) * 56 + (flat >> 3);
  const int m0 = (wg >> 4) * 128, n0 = (wg & 15) * 128;
  f32x4 acc[4][4] = {};
  const int lrow = lane >> 3;
  const int kg = lane & 7;
  for (int ks = 0; ks < 2048; ks += 64) {
#pragma unroll
    for (int q = 0; q < 4; ++q) {
      const int chunk = (w << 2) + q;
      const int row = (chunk << 3) + lrow;
      const int skg = kg ^ (row & 7);
      async16(A + (size_t)(m0 + row) * 2048 + ks + (skg << 3), As + chunk * 512);
      async16(Bw + (size_t)(n0 + row) * 2048 + ks + (skg << 3), Bs + chunk * 512);
    }
    __syncthreads();
#pragma unroll
    for (int kk = 0; kk < 2; ++kk) {
      const int kgl = (kk << 2) + (lane >> 4);
      f16x8 af[4], bf[4];
#pragma unroll
      for (int mi = 0; mi < 4; ++mi) {
        const int r = (wm << 6) + (mi << 4) + (lane & 15);
        af[mi] = *(const f16x8*)(As + r * 64 + ((kgl ^ (r & 7)) << 3));
      }
#pragma unroll
      for (int ni = 0; ni < 4; ++ni) {
        const int r = (wn << 6) + (ni << 4) + (lane & 15);
        bf[ni] = *(const f16x8*)(Bs + r * 64 + ((kgl ^ (r & 7)) << 3));
      }
#pragma unroll
      for (int mi = 0; mi < 4; ++mi)
#pragma unroll
        for (int ni = 0; ni < 4; ++ni)
          acc[mi][ni] = __builtin_amdgcn_mfma_f32_16x16x32_f16(af[mi], bf[ni], acc[mi][ni], 0, 0, 0);
    }
    __syncthreads();
  }
#pragma unroll
  for (int mi = 0; mi < 4; ++mi)
#pragma unroll
    for (int ni = 0; ni < 4; ++ni)
#pragma unroll
      for (int r4 = 0; r4 < 4; ++r4) {
        const int row = m0 + (wm << 6) + (mi << 4) + ((lane >> 4) << 2) + r4;
        const int col = n0 + (wn << 6) + (ni << 4) + (lane & 15);
        Cproj[(size_t)row * 2048 + col] = acc[mi][ni][r4] + bxp[col];
      }
}

// ---------------- persistent recurrence: r12 structure + tagged-data exchange ----------------
// State exchanged as aligned 8B words {tag:u32 | 2xf16}: one L3 round trip for
// observe+load instead of stamp-observe THEN data-load. Tags: c(t)=2t+1, h(t)=2t+2;
// consumer of h at step t expects 2t (memset 0 satisfies t=0). Overwrite safety:
// a producer reaches phase P+2 (overwrite) only after observing all consumers'
// P+1 writes, which follow their P reads (same cycle that made r12's protocol safe).
__global__ __launch_bounds__(256, 1) void k_recur(
    const f16* __restrict__ Wbig, const f16* __restrict__ Wc2h,
    const float* __restrict__ biasb, const float* __restrict__ bc,
    const float* __restrict__ xproj, u64* __restrict__ hTag,
    u64* __restrict__ cbTag, float* __restrict__ lasth,
    const int* __restrict__ tlast, const float* __restrict__ Wd,
    const float* __restrict__ bd, float* __restrict__ out,
    int* __restrict__ bar)
{
  __shared__ alignas(16) f16 hT[2][16 * 512];   // 16 KB each
  __shared__ alignas(16) f16 cT[2][16 * 512];   // persists B(t) -> A(t+1)
  __shared__ alignas(16) float exGO[2][256];    // go, survives A -> B per tile
  __shared__ alignas(16) float ex2[4 * 256];    // B-phase K-split partials
  const int tid = threadIdx.x, lane = tid & 63, w = tid >> 6;
  const int lk = lane >> 4;
  const int bid = blockIdx.x;
  const int pair = bid >> 5, grank = bid & 31;
  const int n0A = grank * 64, n0h = grank * 16;
  const int m0t[2] = {pair * 32, pair * 32 + 16};
  int* const slF = bar + pair * 32;

  // ---- resident weights ----
  f16x8 wG[32];
  {
    const f16* src = Wbig + (size_t)(n0A + w * 16 + (lane & 15)) * 1024 + (lk << 3);
#pragma unroll
    for (int kc = 0; kc < 32; ++kc) wG[kc] = *(const f16x8*)(src + kc * 32);
  }
  f16x8 wO[4];
  {
    const f16* src = Wc2h + (size_t)(n0h + (lane & 15)) * 512 + (lk << 3);
#pragma unroll
    for (int j = 0; j < 4; ++j) wO[j] = *(const f16x8*)(src + (w * 4 + j) * 32);
  }
  // hoisted constants
  const int hq = (lane >> 2) & 3;
  const int browA = (lk << 2) + (lane & 3);
  const int hlA = w * 4 + hq;
  const float4 b4c = *(const float4*)(biasb + 4 * (n0h + hlA));
  const int rowB = tid >> 4, colB = tid & 15;
  const float bco = bc[1024 + n0h + colB];
  const int tlB[2] = {tlast[m0t[0] + rowB], tlast[m0t[1] + rowB]};
  // zero cT (c_{-1} = 0)
  {
    const f16x8 z = {};
#pragma unroll
    for (int j = 0; j < 8; ++j) *(f16x8*)(&cT[0][0] + (((j << 8) + tid) << 3)) = z;
  }
  float creg[2] = {0.f, 0.f};
  __syncthreads();

  for (int t = 0; t < T_; ++t) {
    float4 x4p[2];
#pragma unroll
    for (int tt = 0; tt < 2; ++tt)
      x4p[tt] = *(const float4*)(xproj + (size_t)((m0t[tt] + browA) * T_ + t) * 2048 +
                                 4 * (n0h + hlA));

#pragma unroll
    for (int tt = 0; tt < 2; ++tt) {
      // ===== phase A(tile tt): tagged h staging + gates GEMM over [h | c] =====
      {
        u64 v[16];
        const u64* sp[16];
        int rowc[4], kgc[4];
        const unsigned etag = (unsigned)(2 * t);
#pragma unroll
        for (int c = 0; c < 4; ++c) {
          const int u = (c << 8) + tid;
          rowc[c] = u >> 6; kgc[c] = u & 63;
          const u64* base = hTag + (size_t)(m0t[tt] + rowc[c]) * 256 + (kgc[c] << 2);
#pragma unroll
          for (int q = 0; q < 4; ++q) { sp[c * 4 + q] = base + q; v[c * 4 + q] = aload64(sp[c * 4 + q]); }
        }
        bool ok = false;
        while (!ok) {
          ok = true;
#pragma unroll
          for (int i = 0; i < 16; ++i)
            if ((unsigned)(v[i] >> 32) != etag) { v[i] = aload64(sp[i]); ok = false; }
        }
#pragma unroll
        for (int c = 0; c < 4; ++c) {
          union { f16x8 g; unsigned uu[4]; } ag;
#pragma unroll
          for (int q = 0; q < 4; ++q) ag.uu[q] = (unsigned)v[c * 4 + q];
          *(f16x8*)(&hT[tt][0] + rowc[c] * 512 + ((kgc[c] >> 3) << 6) +
                    (((kgc[c] & 7) ^ (rowc[c] & 7)) << 3)) = ag.g;
        }
      }
      __syncthreads();
      f32x4 acc[2] = {};
      {
        const int ra = lane & 15;
#pragma unroll
        for (int kc = 0; kc < 32; ++kc) {
          const int kgl = ((kc & 1) << 2) + lk;
          const f16* base = (kc < 16) ? (&hT[tt][0] + ((kc >> 1) << 6))
                                      : (&cT[tt][0] + (((kc - 16) >> 1) << 6));
          const f16x8 af = *(const f16x8*)(base + ra * 512 + ((kgl ^ (ra & 7)) << 3));
          acc[kc & 1] = __builtin_amdgcn_mfma_f32_16x16x32_f16(af, wG[kc], acc[kc & 1], 0, 0, 0);
        }
      }
      // epilogue: quad transpose -> (i,f,o,m); c in registers; tagged paired c store
      {
        const f32x4 a = acc[0] + acc[1];
        float a0 = a[0], a1 = a[1], a2 = a[2], a3 = a[3];
        {
          const bool odd = lane & 1;
          float xx = odd ? a0 : a1, yy = odd ? a2 : a3;
          xx = __shfl_xor(xx, 1); yy = __shfl_xor(yy, 1);
          if (odd) { a0 = xx; a2 = yy; } else { a1 = xx; a3 = yy; }
        }
        {
          const bool hi = lane & 2;
          float xx = hi ? a0 : a2, yy = hi ? a1 : a3;
          xx = __shfl_xor(xx, 2); yy = __shfl_xor(yy, 2);
          if (hi) { a0 = xx; a1 = yy; } else { a2 = xx; a3 = yy; }
        }
        const float gi = a0 + b4c.x + x4p[tt].x;
        const float gf = a1 + b4c.y + x4p[tt].y;
        const float go = a2 + b4c.z + x4p[tt].z;
        const float gm = a3 + b4c.w + x4p[tt].w;
        const float cn = sigm(gi) * tanhf(gm) + sigm(gf) * creg[tt];
        creg[tt] = cn;
        exGO[tt][browA * 16 + hlA] = go;
        const float cnP = __shfl_xor(cn, 4);
        if (!(lane & 4)) {
          union { unsigned u; f16 h2[2]; } pk;
          pk.h2[0] = (f16)cn; pk.h2[1] = (f16)cnP;
          astore64(cbTag + (size_t)(m0t[tt] + browA) * 256 + (grank << 3) + (w << 1) + (hq >> 1),
                   ((u64)(unsigned)(2 * t + 1) << 32) | pk.u);
        }
      }
    }

#pragma unroll
    for (int tt = 0; tt < 2; ++tt) {
      // ===== phase B(tile tt): tagged c staging + o-peephole GEMM + tagged h store =====
      {
        u64 v[16];
        const u64* sp[16];
        int rowc[4], kgc[4];
        const unsigned etag = (unsigned)(2 * t + 1);
#pragma unroll
        for (int c = 0; c < 4; ++c) {
          const int u = (c << 8) + tid;
          rowc[c] = u >> 6; kgc[c] = u & 63;
          const u64* base = cbTag + (size_t)(m0t[tt] + rowc[c]) * 256 + (kgc[c] << 2);
#pragma unroll
          for (int q = 0; q < 4; ++q) { sp[c * 4 + q] = base + q; v[c * 4 + q] = aload64(sp[c * 4 + q]); }
        }
        bool ok = false;
        while (!ok) {
          ok = true;
#pragma unroll
          for (int i = 0; i < 16; ++i)
            if ((unsigned)(v[i] >> 32) != etag) { v[i] = aload64(sp[i]); ok = false; }
        }
#pragma unroll
        for (int c = 0; c < 4; ++c) {
          union { f16x8 g; unsigned uu[4]; } ag;
#pragma unroll
          for (int q = 0; q < 4; ++q) ag.uu[q] = (unsigned)v[c * 4 + q];
          *(f16x8*)(&cT[tt][0] + rowc[c] * 512 + ((kgc[c] >> 3) << 6) +
                    (((kgc[c] & 7) ^ (rowc[c] & 7)) << 3)) = ag.g;
        }
      }
      __syncthreads();
      f32x4 accB = {};
      {
        const int ra = lane & 15;
#pragma unroll
        for (int j = 0; j < 4; ++j) {
          const int kc = w * 4 + j;
          const int kgl = ((kc & 1) << 2) + lk;
          const f16x8 af = *(const f16x8*)(&cT[tt][0] + ra * 512 + ((kc >> 1) << 6) +
                                           ((kgl ^ (ra & 7)) << 3));
          accB = __builtin_amdgcn_mfma_f32_16x16x32_f16(af, wO[j], accB, 0, 0, 0);
        }
      }
#pragma unroll
      for (int r4 = 0; r4 < 4; ++r4)
        ex2[w * 256 + ((lk << 2) + r4) * 16 + (lane & 15)] = accB[r4];
      __syncthreads();
      {
        const int ib = rowB * 16 + colB;
        const float sum = (ex2[ib] + ex2[256 + ib]) + (ex2[512 + ib] + ex2[768 + ib]);
        const int cg = n0h + colB;
        const float cn = (float)cT[tt][rowB * 512 + ((cg >> 6) << 6) +
                                       ((((cg >> 3) & 7) ^ (rowB & 7)) << 3) + (cg & 7)];
        const float hv = sigm(sum + exGO[tt][ib] + bco) * cn;
        const float hvo = __shfl_xor(hv, 1);
        if (!(tid & 1)) {
          union { unsigned u; f16 h2[2]; } pk;
          pk.h2[0] = (f16)hv; pk.h2[1] = (f16)hvo;
          astore64(hTag + (size_t)(m0t[tt] + rowB) * 256 + (grank << 3) + (colB >> 1),
                   ((u64)(unsigned)(2 * t + 2) << 32) | pk.u);
        }
        if (t == tlB[tt]) astore(lasth + (size_t)(m0t[tt] + rowB) * 512 + cg, hv);
      }
    }
  }

  // ===== final: signal lasth complete; out[b] = sigmoid(lasth . Wd + bd) =====
  asm volatile("s_waitcnt vmcnt(0)" ::: "memory");
  __syncthreads();
  if (tid == 0) astorei(slF + grank, 1);
  waitSlots(slF, 1);
  if (w == 0) {
    const int b = pair * 32 + grank;
    float s = 0.f;
#pragma unroll
    for (int k = lane; k < 512; k += 64) s += aload(lasth + (size_t)b * 512 + k) * Wd[k];
#pragma unroll
    for (int off = 32; off > 0; off >>= 1) s += __shfl_down(s, off);
    if (lane == 0) out[b] = 1.0f / (1.0f + __expf(-(s + bd[0])));
  }
}

extern "C" void kernel_launch(void* const* d_in, const int* in_sizes, int n_in,
                              void* d_out, int out_size, void* d_ws, size_t ws_size,
                              hipStream_t stream) {
  const float* x   = (const float*)d_in[0];
  const int*   fix = (const int*)d_in[1];
  const float* Wx  = (const float*)d_in[2];
  const float* bx  = (const float*)d_in[3];
  const float* Wh  = (const float*)d_in[4];
  const float* bh  = (const float*)d_in[5];
  const float* Wc  = (const float*)d_in[6];
  const float* bc  = (const float*)d_in[7];
  const float* Wd  = (const float*)d_in[8];
  const float* bd  = (const float*)d_in[9];
  float* out = (float*)d_out;
  char* ws = (char*)d_ws;

  f16*   xg    = (f16*)(ws);                       // 14,680,064
  f16*   Wxh   = (f16*)(ws + 14680064);            //  8,388,608
  float* xproj = (float*)(ws + 23068672);          // 29,360,128
  f16*   Wbig  = (f16*)(ws + 52428800);            //  4,194,304
  f16*   Wc2h  = (f16*)(ws + 56623104);            //    524,288
  float* biasb = (float*)(ws + 57147392);          //      8,192
  float* bxp   = (float*)(ws + 57155584);          //      8,192
  u64*   hTag  = (u64*)(ws + 57163776);            //    524,288
  u64*   cbTag = (u64*)(ws + 57688064);            //    524,288
  float* lasth = (float*)(ws + 58212352);          //    524,288
  int*   tlast = (int*)(ws + 58736640);            //      1,024
  int*   bar   = (int*)(ws + 58737664);            //      8,192

  hipMemsetAsync(hTag, 0, 524288, stream);
  hipMemsetAsync(cbTag, 0, 524288, stream);
  hipMemsetAsync(bar, 0, 8192, stream);

  k_prep_gather<<<1536, 256, 0, stream>>>(Wx, bx, Wh, Wc, bh, bc, fix, x,
                                          Wxh, bxp, Wbig, Wc2h, biasb, xg, tlast);
  k_gemm_big<<<dim3(16, 28), 256, 0, stream>>>(xg, Wxh, bxp, xproj);
  k_recur<<<NBLK, 256, 0, stream>>>(Wbig, Wc2h, biasb, bc, xproj, hTag, cbTag,
                                    lasth, tlast, Wd, bd, out, bar);
}

// Round 14
// 211.603 us; speedup vs baseline: 1.0479x; 1.0479x over previous
//
#include <hip/hip_runtime.h>
#include <cstdint>
#include <cstddef>

#define B_   256
#define T_   14
#define INF_ 2048
#define H_   512
#define HW_  49
#define NG_  2048   /* 4*H */
#define KC_  1024   /* H (h) + H (c) */
#define NBLK 256

typedef __attribute__((ext_vector_type(8))) _Float16 f16x8;
typedef __attribute__((ext_vector_type(4))) _Float16 f16x4;
typedef __attribute__((ext_vector_type(4))) float f32x4;
typedef _Float16 f16;

typedef const void __attribute__((address_space(1))) gvoid_t;
typedef void __attribute__((address_space(3))) svoid_t;

__device__ __forceinline__ void async16(const void* g, void* l) {
  __builtin_amdgcn_global_load_lds((gvoid_t*)g, (svoid_t*)l, 16, 0, 0);
}

__device__ __forceinline__ float sigm(float x) { return 1.0f / (1.0f + __expf(-x)); }

// ---- agent-scope (L3-coherent) relaxed accessors — the PROVEN r7/r12 data path ----
__device__ __forceinline__ float aload(const float* p) {
  return __hip_atomic_load(p, __ATOMIC_RELAXED, __HIP_MEMORY_SCOPE_AGENT);
}
__device__ __forceinline__ int aloadi(const int* p) {
  return __hip_atomic_load(p, __ATOMIC_RELAXED, __HIP_MEMORY_SCOPE_AGENT);
}
__device__ __forceinline__ unsigned long long aload64(const void* p) {
  return __hip_atomic_load((const unsigned long long*)p, __ATOMIC_RELAXED, __HIP_MEMORY_SCOPE_AGENT);
}
__device__ __forceinline__ void astore(float* p, float v) {
  __hip_atomic_store(p, v, __ATOMIC_RELAXED, __HIP_MEMORY_SCOPE_AGENT);
}
__device__ __forceinline__ void astore32(void* p, unsigned v) {
  __hip_atomic_store((unsigned*)p, v, __ATOMIC_RELAXED, __HIP_MEMORY_SCOPE_AGENT);
}
__device__ __forceinline__ void astorei(int* p, int v) {
  __hip_atomic_store(p, v, __ATOMIC_RELAXED, __HIP_MEMORY_SCOPE_AGENT);
}

// slot barrier (r7-proven): producer stamps own slot; consumers poll 32 slots
__device__ __forceinline__ void waitSlots(const int* slots, const int target) {
  const int* p = slots + (threadIdx.x & 31);
  for (;;) {
    const int v = aloadi(p);
    if (__all(v >= target)) break;
    __builtin_amdgcn_s_sleep(1);
  }
}

// ---------------- fused prep (weight conversion) + gather ----------------
__global__ __launch_bounds__(256) void k_prep_gather(
    const float* __restrict__ Wx, const float* __restrict__ bx,
    const float* __restrict__ Wh, const float* __restrict__ Wc,
    const float* __restrict__ bh, const float* __restrict__ bc,
    const int* __restrict__ fix, const float* __restrict__ x,
    f16* __restrict__ Wxh, float* __restrict__ bxp,
    f16* __restrict__ Wbig, f16* __restrict__ Wc2h,
    float* __restrict__ biasb, f16* __restrict__ xg, int* __restrict__ tlast)
{
  const int bid = blockIdx.x;
  const int tid = threadIdx.x;
  if (bid < 1024) {
    __shared__ float rows[256 * 49];
    __shared__ int wv[T_];
    __shared__ int anyS;
    const int b = bid >> 2, part = bid & 3;
    int a = 0;
    for (int i = tid; i < B_ * T_; i += 256) a |= fix[2 * i + 1];
    if (tid == 0) anyS = 0;
    __syncthreads();
    if (a) anyS = 1;
    __syncthreads();
    const int is64 = (anyS == 0);
    if (tid < T_) wv[tid] = is64 ? fix[2 * (b * T_ + tid)] : fix[b * T_ + tid];
    __syncthreads();
    if (part == 0 && tid == 0) {
      int cnt = 0;
      for (int t = 0; t < T_; ++t) cnt += (wv[t] == 0);
      tlast[b] = (cnt < T_) ? (T_ - 1 - cnt) : (T_ - 1);
    }
    const float* xb = x + (size_t)b * (INF_ * HW_);
    for (int c = 0; c < 2; ++c) {
      const int ch = part * 2 + c;
      if (c) __syncthreads();
      const float4* src = (const float4*)(xb + (size_t)ch * 256 * 49);
      float4* dst4 = (float4*)rows;
      for (int i = tid; i < 3136; i += 256) dst4[i] = src[i];
      __syncthreads();
#pragma unroll
      for (int t = 0; t < T_; ++t)
        xg[(size_t)(b * T_ + t) * INF_ + ch * 256 + tid] = (f16)rows[tid * 49 + wv[t]];
    }
  } else {
    const int tid2 = (bid - 1024) * 256 + tid;
    const int nth = 512 * 256;
    for (int i = tid2; i < 4 * H_ * INF_; i += nth) {
      const int n = i >> 11, k = i & 2047;
      const int g = n & 3, h = n >> 2;
      Wxh[i] = (f16)Wx[((size_t)(g * H_ + h)) * INF_ + k];
    }
    for (int i = tid2; i < NG_ * KC_; i += nth) {
      const int n = i >> 10, k = i & 1023;
      const int g = n & 3, h = n >> 2;
      float v;
      if (k < H_) v = Wh[((size_t)(g * H_ + h)) * H_ + k];
      else {
        const int kk = k - H_;
        v = (g == 0) ? Wc[h * H_ + kk] : (g == 1) ? Wc[H_ * H_ + h * H_ + kk] : 0.0f;
      }
      Wbig[i] = (f16)v;
    }
    for (int i = tid2; i < H_ * H_; i += nth) Wc2h[i] = (f16)Wc[2 * H_ * H_ + i];
    for (int i = tid2; i < NG_; i += nth) {
      const int g = i & 3, h = i >> 2;
      biasb[i] = bh[g * H_ + h] + ((g == 0) ? bc[h] : (g == 1) ? bc[H_ + h] : 0.0f);
      bxp[i] = bx[g * H_ + h];
    }
  }
}

// ---------------- big GEMM: xproj16[3584][2048] = (f16)(xg @ Wxh^T + bxp) ----------------
__global__ __launch_bounds__(256) void k_gemm_big(
    const f16* __restrict__ A, const f16* __restrict__ Bw,
    const float* __restrict__ bxp, f16* __restrict__ Cproj)
{
  __shared__ alignas(16) f16 As[128 * 64];
  __shared__ alignas(16) f16 Bs[128 * 64];
  const int tid = threadIdx.x;
  const int lane = tid & 63;
  const int w = tid >> 6;
  const int wm = w >> 1, wn = w & 1;
  const int flat = blockIdx.y * 16 + blockIdx.x;
  const int wg = (flat & 7) * 56 + (flat >> 3);
  const int m0 = (wg >> 4) * 128, n0 = (wg & 15) * 128;
  f32x4 acc[4][4] = {};
  const int lrow = lane >> 3;
  const int kg = lane & 7;
  for (int ks = 0; ks < 2048; ks += 64) {
#pragma unroll
    for (int q = 0; q < 4; ++q) {
      const int chunk = (w << 2) + q;
      const int row = (chunk << 3) + lrow;
      const int skg = kg ^ (row & 7);
      async16(A + (size_t)(m0 + row) * 2048 + ks + (skg << 3), As + chunk * 512);
      async16(Bw + (size_t)(n0 + row) * 2048 + ks + (skg << 3), Bs + chunk * 512);
    }
    __syncthreads();
#pragma unroll
    for (int kk = 0; kk < 2; ++kk) {
      const int kgl = (kk << 2) + (lane >> 4);
      f16x8 af[4], bf[4];
#pragma unroll
      for (int mi = 0; mi < 4; ++mi) {
        const int r = (wm << 6) + (mi << 4) + (lane & 15);
        af[mi] = *(const f16x8*)(As + r * 64 + ((kgl ^ (r & 7)) << 3));
      }
#pragma unroll
      for (int ni = 0; ni < 4; ++ni) {
        const int r = (wn << 6) + (ni << 4) + (lane & 15);
        bf[ni] = *(const f16x8*)(Bs + r * 64 + ((kgl ^ (r & 7)) << 3));
      }
#pragma unroll
      for (int mi = 0; mi < 4; ++mi)
#pragma unroll
        for (int ni = 0; ni < 4; ++ni)
          acc[mi][ni] = __builtin_amdgcn_mfma_f32_16x16x32_f16(af[mi], bf[ni], acc[mi][ni], 0, 0, 0);
    }
    __syncthreads();
  }
#pragma unroll
  for (int mi = 0; mi < 4; ++mi)
#pragma unroll
    for (int ni = 0; ni < 4; ++ni)
#pragma unroll
      for (int r4 = 0; r4 < 4; ++r4) {
        const int row = m0 + (wm << 6) + (mi << 4) + ((lane >> 4) << 2) + r4;
        const int col = n0 + (wn << 6) + (ni << 4) + (lane & 15);
        Cproj[(size_t)row * 2048 + col] = (f16)(acc[mi][ni][r4] + bxp[col]);
      }
}

// ---------------- persistent recurrence: r12 verbatim (f16 xproj prefetch only) ----------------
__global__ __launch_bounds__(256, 1) void k_recur(
    const f16* __restrict__ Wbig, const f16* __restrict__ Wc2h,
    const float* __restrict__ biasb, const float* __restrict__ bc,
    const f16* __restrict__ xproj, f16* __restrict__ h16,
    f16* __restrict__ cb16, float* __restrict__ lasth,
    const int* __restrict__ tlast, const float* __restrict__ Wd,
    const float* __restrict__ bd, float* __restrict__ out,
    int* __restrict__ bar)
{
  __shared__ alignas(16) f16 hT[2][16 * 512];   // 16 KB each
  __shared__ alignas(16) f16 cT[2][16 * 512];   // persists B(t) -> A(t+1)
  __shared__ alignas(16) float exCN[256];       // cn scratch (reused per tile)
  __shared__ alignas(16) float exGO[2][256];    // go, survives A -> B per tile
  __shared__ alignas(16) float ex2[4 * 256];    // B-phase K-split partials
  const int tid = threadIdx.x, lane = tid & 63, w = tid >> 6;
  const int lk = lane >> 4;
  const int bid = blockIdx.x;
  const int pair = bid >> 5, grank = bid & 31;
  const int n0A = grank * 64, n0h = grank * 16;
  const int m0t[2] = {pair * 32, pair * 32 + 16};
  int* const sl[2] = {bar + (2 * pair) * 64, bar + (2 * pair + 1) * 64};

  // ---- resident weights ----
  f16x8 wG[32];   // gates B-operand: this wave's 16 gate-cols x K=1024
  {
    const f16* src = Wbig + (size_t)(n0A + w * 16 + (lane & 15)) * 1024 + (lk << 3);
#pragma unroll
    for (int kc = 0; kc < 32; ++kc) wG[kc] = *(const f16x8*)(src + kc * 32);
  }
  f16x8 wO[4];    // o-peephole: 16 h-cols x this wave's K-chunk (128)
  {
    const f16* src = Wc2h + (size_t)(n0h + (lane & 15)) * 512 + (lk << 3);
#pragma unroll
    for (int j = 0; j < 4; ++j) wO[j] = *(const f16x8*)(src + (w * 4 + j) * 32);
  }
  // hoisted constants
  const int hq = (lane >> 2) & 3;
  const int browA = (lk << 2) + (lane & 3);        // A-epilogue batch row (0..15)
  const int hlA = w * 4 + hq;                      // A-epilogue h-col within slice
  const float4 b4c = *(const float4*)(biasb + 4 * (n0h + hlA));
  const int rowB = tid >> 4, colB = tid & 15;      // B-epilogue (row, h-col)
  const float bco = bc[1024 + n0h + colB];
  const int tlB[2] = {tlast[m0t[0] + rowB], tlast[m0t[1] + rowB]};
  // zero cT (c_{-1} = 0)
  {
    const f16x8 z = {};
#pragma unroll
    for (int j = 0; j < 8; ++j) *(f16x8*)(&cT[0][0] + (((j << 8) + tid) << 3)) = z;
  }
  float creg[2] = {0.f, 0.f};
  __syncthreads();

  for (int t = 0; t < T_; ++t) {
    // prefetch xproj (f16x4 = 8B) for both tiles, in flight across waits
    float4 x4p[2];
#pragma unroll
    for (int tt = 0; tt < 2; ++tt) {
      const f16x4 xr = *(const f16x4*)(xproj + (size_t)((m0t[tt] + browA) * T_ + t) * 2048 +
                                       4 * (n0h + hlA));
      x4p[tt] = make_float4((float)xr[0], (float)xr[1], (float)xr[2], (float)xr[3]);
    }

#pragma unroll
    for (int tt = 0; tt < 2; ++tt) {
      // ===== phase A(tile tt): gates GEMM over [h | c] =====
      if (t) waitSlots(sl[tt], 2 * t);
      // stage hT[tt] [16][512] coherently (4 units of 8 f16 per thread)
#pragma unroll
      for (int j = 0; j < 4; ++j) {
        const int u = (j << 8) + tid;
        const int row = u >> 6, kg = u & 63;
        const f16* src = h16 + (size_t)(m0t[tt] + row) * 512 + (kg << 3);
        union { f16x8 v; unsigned long long q[2]; } u2;
        u2.q[0] = aload64(src);
        u2.q[1] = aload64(src + 4);
        *(f16x8*)(&hT[tt][0] + row * 512 + ((kg >> 3) << 6) + (((kg & 7) ^ (row & 7)) << 3)) = u2.v;
      }
      __syncthreads();
      f32x4 acc[2] = {};
      {
        const int ra = lane & 15;
#pragma unroll
        for (int kc = 0; kc < 32; ++kc) {
          const int kgl = ((kc & 1) << 2) + lk;
          const f16* base = (kc < 16) ? (&hT[tt][0] + ((kc >> 1) << 6))
                                      : (&cT[tt][0] + (((kc - 16) >> 1) << 6));
          const f16x8 af = *(const f16x8*)(base + ra * 512 + ((kgl ^ (ra & 7)) << 3));
          acc[kc & 1] = __builtin_amdgcn_mfma_f32_16x16x32_f16(af, wG[kc], acc[kc & 1], 0, 0, 0);
        }
      }
      // epilogue: quad transpose -> (i,f,o,m) per (b,h)
      {
        const f32x4 a = acc[0] + acc[1];
        float a0 = a[0], a1 = a[1], a2 = a[2], a3 = a[3];
        {
          const bool odd = lane & 1;
          float xx = odd ? a0 : a1, yy = odd ? a2 : a3;
          xx = __shfl_xor(xx, 1); yy = __shfl_xor(yy, 1);
          if (odd) { a0 = xx; a2 = yy; } else { a1 = xx; a3 = yy; }
        }
        {
          const bool hi = lane & 2;
          float xx = hi ? a0 : a2, yy = hi ? a1 : a3;
          xx = __shfl_xor(xx, 2); yy = __shfl_xor(yy, 2);
          if (hi) { a0 = xx; a1 = yy; } else { a2 = xx; a3 = yy; }
        }
        const float gi = a0 + b4c.x + x4p[tt].x;
        const float gf = a1 + b4c.y + x4p[tt].y;
        const float go = a2 + b4c.z + x4p[tt].z;
        const float gm = a3 + b4c.w + x4p[tt].w;
        const float cn = sigm(gi) * tanhf(gm) + sigm(gf) * creg[tt];
        creg[tt] = cn;
        exCN[browA * 16 + hlA] = cn;
        exGO[tt][browA * 16 + hlA] = go;
      }
      __syncthreads();
      if (tid < 128) {   // pack + store c (16 rows x 8 col-pairs)
        const int rowe = tid >> 3, pr = tid & 7;
        const float2 cp = *(const float2*)(exCN + rowe * 16 + (pr << 1));
        union { unsigned u; f16 h2[2]; } pk;
        pk.h2[0] = (f16)cp.x; pk.h2[1] = (f16)cp.y;
        astore32(cb16 + (size_t)(m0t[tt] + rowe) * 512 + n0h + (pr << 1), pk.u);
      }
      __syncthreads();   // drains all waves' vmcnt -> c globally visible
      if (tid == 0)
        astorei(sl[tt] + grank, 2 * t + 1);
    }

#pragma unroll
    for (int tt = 0; tt < 2; ++tt) {
      // ===== phase B(tile tt): o-peephole GEMM + h write =====
      waitSlots(sl[tt], 2 * t + 1);
      // stage cT[tt] (new c; persists as next step's A operand)
#pragma unroll
      for (int j = 0; j < 4; ++j) {
        const int u = (j << 8) + tid;
        const int row = u >> 6, kg = u & 63;
        const f16* src = cb16 + (size_t)(m0t[tt] + row) * 512 + (kg << 3);
        union { f16x8 v; unsigned long long q[2]; } u2;
        u2.q[0] = aload64(src);
        u2.q[1] = aload64(src + 4);
        *(f16x8*)(&cT[tt][0] + row * 512 + ((kg >> 3) << 6) + (((kg & 7) ^ (row & 7)) << 3)) = u2.v;
      }
      __syncthreads();
      f32x4 accB = {};
      {
        const int ra = lane & 15;
#pragma unroll
        for (int j = 0; j < 4; ++j) {
          const int kc = w * 4 + j;
          const int kgl = ((kc & 1) << 2) + lk;
          const f16x8 af = *(const f16x8*)(&cT[tt][0] + ra * 512 + ((kc >> 1) << 6) +
                                           ((kgl ^ (ra & 7)) << 3));
          accB = __builtin_amdgcn_mfma_f32_16x16x32_f16(af, wO[j], accB, 0, 0, 0);
        }
      }
#pragma unroll
      for (int r4 = 0; r4 < 4; ++r4)
        ex2[w * 256 + ((lk << 2) + r4) * 16 + (lane & 15)] = accB[r4];
      __syncthreads();
      {
        const int ib = rowB * 16 + colB;
        const float sum = (ex2[ib] + ex2[256 + ib]) + (ex2[512 + ib] + ex2[768 + ib]);
        const int cg = n0h + colB;
        const float cn = (float)cT[tt][rowB * 512 + ((cg >> 6) << 6) +
                                       ((((cg >> 3) & 7) ^ (rowB & 7)) << 3) + (cg & 7)];
        const float hv = sigm(sum + exGO[tt][ib] + bco) * cn;
        const float hvo = __shfl_xor(hv, 1);
        if (!(tid & 1)) {
          union { unsigned u; f16 h2[2]; } pk;
          pk.h2[0] = (f16)hv; pk.h2[1] = (f16)hvo;
          astore32(h16 + (size_t)(m0t[tt] + rowB) * 512 + (cg & ~1), pk.u);
        }
        if (t == tlB[tt]) astore(lasth + (size_t)(m0t[tt] + rowB) * 512 + cg, hv);
      }
      __syncthreads();   // drains vmcnt -> h globally visible
      if (tid == 0)
        astorei(sl[tt] + grank, 2 * t + 2);
    }
  }

  // ===== final: out[b] = sigmoid(lasth . Wd + bd), one row per block =====
  waitSlots(sl[0], 2 * T_);
  waitSlots(sl[1], 2 * T_);
  if (w == 0) {
    const int b = pair * 32 + grank;
    float s = 0.f;
#pragma unroll
    for (int k = lane; k < 512; k += 64) s += aload(lasth + (size_t)b * 512 + k) * Wd[k];
#pragma unroll
    for (int off = 32; off > 0; off >>= 1) s += __shfl_down(s, off);
    if (lane == 0) out[b] = 1.0f / (1.0f + __expf(-(s + bd[0])));
  }
}

extern "C" void kernel_launch(void* const* d_in, const int* in_sizes, int n_in,
                              void* d_out, int out_size, void* d_ws, size_t ws_size,
                              hipStream_t stream) {
  const float* x   = (const float*)d_in[0];
  const int*   fix = (const int*)d_in[1];
  const float* Wx  = (const float*)d_in[2];
  const float* bx  = (const float*)d_in[3];
  const float* Wh  = (const float*)d_in[4];
  const float* bh  = (const float*)d_in[5];
  const float* Wc  = (const float*)d_in[6];
  const float* bc  = (const float*)d_in[7];
  const float* Wd  = (const float*)d_in[8];
  const float* bd  = (const float*)d_in[9];
  float* out = (float*)d_out;
  char* ws = (char*)d_ws;

  f16*   xg    = (f16*)(ws);                       // 14,680,064
  f16*   Wxh   = (f16*)(ws + 14680064);            //  8,388,608
  f16*   xproj = (f16*)(ws + 23068672);            // 14,680,064 (f16 now)
  f16*   Wbig  = (f16*)(ws + 52428800);            //  4,194,304
  f16*   Wc2h  = (f16*)(ws + 56623104);            //    524,288
  float* biasb = (float*)(ws + 57147392);          //      8,192
  float* bxp   = (float*)(ws + 57155584);          //      8,192
  f16*   h16   = (f16*)(ws + 57163776);            //    262,144
  f16*   cb16  = (f16*)(ws + 57425920);            //    262,144
  float* lasth = (float*)(ws + 57688064);          //    524,288
  int*   tlast = (int*)(ws + 58212352);            //      1,024
  int*   bar   = (int*)(ws + 58213376);            //      8,192

  hipMemsetAsync(h16, 0, 262144, stream);
  hipMemsetAsync(cb16, 0, 262144, stream);
  hipMemsetAsync(bar, 0, 8192, stream);

  k_prep_gather<<<1536, 256, 0, stream>>>(Wx, bx, Wh, Wc, bh, bc, fix, x,
                                          Wxh, bxp, Wbig, Wc2h, biasb, xg, tlast);
  k_gemm_big<<<dim3(16, 28), 256, 0, stream>>>(xg, Wxh, bxp, xproj);
  k_recur<<<NBLK, 256, 0, stream>>>(Wbig, Wc2h, biasb, bc, xproj, h16, cb16,
                                    lasth, tlast, Wd, bd, out, bar);
}

// Round 15
// 207.180 us; speedup vs baseline: 1.0703x; 1.0213x over previous
//
#include <hip/hip_runtime.h>
#include <cstdint>
#include <cstddef>

#define B_   256
#define T_   14
#define INF_ 2048
#define H_   512
#define HW_  49
#define NG_  2048   /* 4*H */
#define KC_  1024   /* H (h) + H (c) */
#define NBLK 256

typedef __attribute__((ext_vector_type(8))) _Float16 f16x8;
typedef __attribute__((ext_vector_type(4))) _Float16 f16x4;
typedef __attribute__((ext_vector_type(4))) float f32x4;
typedef _Float16 f16;

typedef const void __attribute__((address_space(1))) gvoid_t;
typedef void __attribute__((address_space(3))) svoid_t;

__device__ __forceinline__ void async16(const void* g, void* l) {
  __builtin_amdgcn_global_load_lds((gvoid_t*)g, (svoid_t*)l, 16, 0, 0);
}

__device__ __forceinline__ float sigm(float x) { return 1.0f / (1.0f + __expf(-x)); }

// ---- agent-scope (L3-coherent) relaxed accessors — the PROVEN r7/r12 data path ----
__device__ __forceinline__ float aload(const float* p) {
  return __hip_atomic_load(p, __ATOMIC_RELAXED, __HIP_MEMORY_SCOPE_AGENT);
}
__device__ __forceinline__ int aloadi(const int* p) {
  return __hip_atomic_load(p, __ATOMIC_RELAXED, __HIP_MEMORY_SCOPE_AGENT);
}
__device__ __forceinline__ unsigned long long aload64(const void* p) {
  return __hip_atomic_load((const unsigned long long*)p, __ATOMIC_RELAXED, __HIP_MEMORY_SCOPE_AGENT);
}
__device__ __forceinline__ void astore(float* p, float v) {
  __hip_atomic_store(p, v, __ATOMIC_RELAXED, __HIP_MEMORY_SCOPE_AGENT);
}
__device__ __forceinline__ void astore32(void* p, unsigned v) {
  __hip_atomic_store((unsigned*)p, v, __ATOMIC_RELAXED, __HIP_MEMORY_SCOPE_AGENT);
}
__device__ __forceinline__ void astorei(int* p, int v) {
  __hip_atomic_store(p, v, __ATOMIC_RELAXED, __HIP_MEMORY_SCOPE_AGENT);
}

// slot barrier (r7-proven): producer stamps own slot; consumers poll 32 slots
__device__ __forceinline__ void waitSlots(const int* slots, const int target) {
  const int* p = slots + (threadIdx.x & 31);
  for (;;) {
    const int v = aloadi(p);
    if (__all(v >= target)) break;
    __builtin_amdgcn_s_sleep(1);
  }
}

// ---------------- fused prep (weight conversion) + gather ----------------
__global__ __launch_bounds__(256) void k_prep_gather(
    const float* __restrict__ Wx, const float* __restrict__ bx,
    const float* __restrict__ Wh, const float* __restrict__ Wc,
    const float* __restrict__ bh, const float* __restrict__ bc,
    const int* __restrict__ fix, const float* __restrict__ x,
    f16* __restrict__ Wxh, float* __restrict__ bxp,
    f16* __restrict__ Wbig, f16* __restrict__ Wc2h,
    float* __restrict__ biasb, f16* __restrict__ xg, int* __restrict__ tlast)
{
  const int bid = blockIdx.x;
  const int tid = threadIdx.x;
  if (bid < 1024) {
    __shared__ float rows[256 * 49];
    __shared__ int wv[T_];
    __shared__ int anyS;
    const int b = bid >> 2, part = bid & 3;
    int a = 0;
    for (int i = tid; i < B_ * T_; i += 256) a |= fix[2 * i + 1];
    if (tid == 0) anyS = 0;
    __syncthreads();
    if (a) anyS = 1;
    __syncthreads();
    const int is64 = (anyS == 0);
    if (tid < T_) wv[tid] = is64 ? fix[2 * (b * T_ + tid)] : fix[b * T_ + tid];
    __syncthreads();
    if (part == 0 && tid == 0) {
      int cnt = 0;
      for (int t = 0; t < T_; ++t) cnt += (wv[t] == 0);
      tlast[b] = (cnt < T_) ? (T_ - 1 - cnt) : (T_ - 1);
    }
    const float* xb = x + (size_t)b * (INF_ * HW_);
    for (int c = 0; c < 2; ++c) {
      const int ch = part * 2 + c;
      if (c) __syncthreads();
      const float4* src = (const float4*)(xb + (size_t)ch * 256 * 49);
      float4* dst4 = (float4*)rows;
      for (int i = tid; i < 3136; i += 256) dst4[i] = src[i];
      __syncthreads();
#pragma unroll
      for (int t = 0; t < T_; ++t)
        xg[(size_t)(b * T_ + t) * INF_ + ch * 256 + tid] = (f16)rows[tid * 49 + wv[t]];
    }
  } else {
    const int tid2 = (bid - 1024) * 256 + tid;
    const int nth = 512 * 256;
    for (int i = tid2; i < 4 * H_ * INF_; i += nth) {
      const int n = i >> 11, k = i & 2047;
      const int g = n & 3, h = n >> 2;
      Wxh[i] = (f16)Wx[((size_t)(g * H_ + h)) * INF_ + k];
    }
    for (int i = tid2; i < NG_ * KC_; i += nth) {
      const int n = i >> 10, k = i & 1023;
      const int g = n & 3, h = n >> 2;
      float v;
      if (k < H_) v = Wh[((size_t)(g * H_ + h)) * H_ + k];
      else {
        const int kk = k - H_;
        v = (g == 0) ? Wc[h * H_ + kk] : (g == 1) ? Wc[H_ * H_ + h * H_ + kk] : 0.0f;
      }
      Wbig[i] = (f16)v;
    }
    for (int i = tid2; i < H_ * H_; i += nth) Wc2h[i] = (f16)Wc[2 * H_ * H_ + i];
    for (int i = tid2; i < NG_; i += nth) {
      const int g = i & 3, h = i >> 2;
      biasb[i] = bh[g * H_ + h] + ((g == 0) ? bc[h] : (g == 1) ? bc[H_ + h] : 0.0f);
      bxp[i] = bx[g * H_ + h];
    }
  }
}

// ---------------- big GEMM: xproj16[3584][2048] = (f16)(xg @ Wxh^T + bxp) ----------------
// __launch_bounds__(256, 2): cap at 128 VGPR -> 2 blocks/CU -> all 448 blocks
// resident in one dispatch wave; co-resident block hides the per-K-step barrier drain.
__global__ __launch_bounds__(256, 2) void k_gemm_big(
    const f16* __restrict__ A, const f16* __restrict__ Bw,
    const float* __restrict__ bxp, f16* __restrict__ Cproj)
{
  __shared__ alignas(16) f16 As[128 * 64];
  __shared__ alignas(16) f16 Bs[128 * 64];
  const int tid = threadIdx.x;
  const int lane = tid & 63;
  const int w = tid >> 6;
  const int wm = w >> 1, wn = w & 1;
  const int flat = blockIdx.y * 16 + blockIdx.x;
  const int wg = (flat & 7) * 56 + (flat >> 3);
  const int m0 = (wg >> 4) * 128, n0 = (wg & 15) * 128;
  f32x4 acc[4][4] = {};
  const int lrow = lane >> 3;
  const int kg = lane & 7;
  for (int ks = 0; ks < 2048; ks += 64) {
#pragma unroll
    for (int q = 0; q < 4; ++q) {
      const int chunk = (w << 2) + q;
      const int row = (chunk << 3) + lrow;
      const int skg = kg ^ (row & 7);
      async16(A + (size_t)(m0 + row) * 2048 + ks + (skg << 3), As + chunk * 512);
      async16(Bw + (size_t)(n0 + row) * 2048 + ks + (skg << 3), Bs + chunk * 512);
    }
    __syncthreads();
#pragma unroll
    for (int kk = 0; kk < 2; ++kk) {
      const int kgl = (kk << 2) + (lane >> 4);
      f16x8 af[4], bf[4];
#pragma unroll
      for (int mi = 0; mi < 4; ++mi) {
        const int r = (wm << 6) + (mi << 4) + (lane & 15);
        af[mi] = *(const f16x8*)(As + r * 64 + ((kgl ^ (r & 7)) << 3));
      }
#pragma unroll
      for (int ni = 0; ni < 4; ++ni) {
        const int r = (wn << 6) + (ni << 4) + (lane & 15);
        bf[ni] = *(const f16x8*)(Bs + r * 64 + ((kgl ^ (r & 7)) << 3));
      }
#pragma unroll
      for (int mi = 0; mi < 4; ++mi)
#pragma unroll
        for (int ni = 0; ni < 4; ++ni)
          acc[mi][ni] = __builtin_amdgcn_mfma_f32_16x16x32_f16(af[mi], bf[ni], acc[mi][ni], 0, 0, 0);
    }
    __syncthreads();
  }
#pragma unroll
  for (int mi = 0; mi < 4; ++mi)
#pragma unroll
    for (int ni = 0; ni < 4; ++ni)
#pragma unroll
      for (int r4 = 0; r4 < 4; ++r4) {
        const int row = m0 + (wm << 6) + (mi << 4) + ((lane >> 4) << 2) + r4;
        const int col = n0 + (wn << 6) + (ni << 4) + (lane & 15);
        Cproj[(size_t)row * 2048 + col] = (f16)(acc[mi][ni][r4] + bxp[col]);
      }
}

// ---------------- persistent recurrence: r12 verbatim (f16 xproj prefetch only) ----------------
__global__ __launch_bounds__(256, 1) void k_recur(
    const f16* __restrict__ Wbig, const f16* __restrict__ Wc2h,
    const float* __restrict__ biasb, const float* __restrict__ bc,
    const f16* __restrict__ xproj, f16* __restrict__ h16,
    f16* __restrict__ cb16, float* __restrict__ lasth,
    const int* __restrict__ tlast, const float* __restrict__ Wd,
    const float* __restrict__ bd, float* __restrict__ out,
    int* __restrict__ bar)
{
  __shared__ alignas(16) f16 hT[2][16 * 512];   // 16 KB each
  __shared__ alignas(16) f16 cT[2][16 * 512];   // persists B(t) -> A(t+1)
  __shared__ alignas(16) float exCN[256];       // cn scratch (reused per tile)
  __shared__ alignas(16) float exGO[2][256];    // go, survives A -> B per tile
  __shared__ alignas(16) float ex2[4 * 256];    // B-phase K-split partials
  const int tid = threadIdx.x, lane = tid & 63, w = tid >> 6;
  const int lk = lane >> 4;
  const int bid = blockIdx.x;
  const int pair = bid >> 5, grank = bid & 31;
  const int n0A = grank * 64, n0h = grank * 16;
  const int m0t[2] = {pair * 32, pair * 32 + 16};
  int* const sl[2] = {bar + (2 * pair) * 64, bar + (2 * pair + 1) * 64};

  // ---- resident weights ----
  f16x8 wG[32];   // gates B-operand: this wave's 16 gate-cols x K=1024
  {
    const f16* src = Wbig + (size_t)(n0A + w * 16 + (lane & 15)) * 1024 + (lk << 3);
#pragma unroll
    for (int kc = 0; kc < 32; ++kc) wG[kc] = *(const f16x8*)(src + kc * 32);
  }
  f16x8 wO[4];    // o-peephole: 16 h-cols x this wave's K-chunk (128)
  {
    const f16* src = Wc2h + (size_t)(n0h + (lane & 15)) * 512 + (lk << 3);
#pragma unroll
    for (int j = 0; j < 4; ++j) wO[j] = *(const f16x8*)(src + (w * 4 + j) * 32);
  }
  // hoisted constants
  const int hq = (lane >> 2) & 3;
  const int browA = (lk << 2) + (lane & 3);        // A-epilogue batch row (0..15)
  const int hlA = w * 4 + hq;                      // A-epilogue h-col within slice
  const float4 b4c = *(const float4*)(biasb + 4 * (n0h + hlA));
  const int rowB = tid >> 4, colB = tid & 15;      // B-epilogue (row, h-col)
  const float bco = bc[1024 + n0h + colB];
  const int tlB[2] = {tlast[m0t[0] + rowB], tlast[m0t[1] + rowB]};
  // zero cT (c_{-1} = 0)
  {
    const f16x8 z = {};
#pragma unroll
    for (int j = 0; j < 8; ++j) *(f16x8*)(&cT[0][0] + (((j << 8) + tid) << 3)) = z;
  }
  float creg[2] = {0.f, 0.f};
  __syncthreads();

  for (int t = 0; t < T_; ++t) {
    // prefetch xproj (f16x4 = 8B) for both tiles, in flight across waits
    float4 x4p[2];
#pragma unroll
    for (int tt = 0; tt < 2; ++tt) {
      const f16x4 xr = *(const f16x4*)(xproj + (size_t)((m0t[tt] + browA) * T_ + t) * 2048 +
                                       4 * (n0h + hlA));
      x4p[tt] = make_float4((float)xr[0], (float)xr[1], (float)xr[2], (float)xr[3]);
    }

#pragma unroll
    for (int tt = 0; tt < 2; ++tt) {
      // ===== phase A(tile tt): gates GEMM over [h | c] =====
      if (t) waitSlots(sl[tt], 2 * t);
      // stage hT[tt] [16][512] coherently (4 units of 8 f16 per thread)
#pragma unroll
      for (int j = 0; j < 4; ++j) {
        const int u = (j << 8) + tid;
        const int row = u >> 6, kg = u & 63;
        const f16* src = h16 + (size_t)(m0t[tt] + row) * 512 + (kg << 3);
        union { f16x8 v; unsigned long long q[2]; } u2;
        u2.q[0] = aload64(src);
        u2.q[1] = aload64(src + 4);
        *(f16x8*)(&hT[tt][0] + row * 512 + ((kg >> 3) << 6) + (((kg & 7) ^ (row & 7)) << 3)) = u2.v;
      }
      __syncthreads();
      f32x4 acc[2] = {};
      {
        const int ra = lane & 15;
#pragma unroll
        for (int kc = 0; kc < 32; ++kc) {
          const int kgl = ((kc & 1) << 2) + lk;
          const f16* base = (kc < 16) ? (&hT[tt][0] + ((kc >> 1) << 6))
                                      : (&cT[tt][0] + (((kc - 16) >> 1) << 6));
          const f16x8 af = *(const f16x8*)(base + ra * 512 + ((kgl ^ (ra & 7)) << 3));
          acc[kc & 1] = __builtin_amdgcn_mfma_f32_16x16x32_f16(af, wG[kc], acc[kc & 1], 0, 0, 0);
        }
      }
      // epilogue: quad transpose -> (i,f,o,m) per (b,h)
      {
        const f32x4 a = acc[0] + acc[1];
        float a0 = a[0], a1 = a[1], a2 = a[2], a3 = a[3];
        {
          const bool odd = lane & 1;
          float xx = odd ? a0 : a1, yy = odd ? a2 : a3;
          xx = __shfl_xor(xx, 1); yy = __shfl_xor(yy, 1);
          if (odd) { a0 = xx; a2 = yy; } else { a1 = xx; a3 = yy; }
        }
        {
          const bool hi = lane & 2;
          float xx = hi ? a0 : a2, yy = hi ? a1 : a3;
          xx = __shfl_xor(xx, 2); yy = __shfl_xor(yy, 2);
          if (hi) { a0 = xx; a1 = yy; } else { a2 = xx; a3 = yy; }
        }
        const float gi = a0 + b4c.x + x4p[tt].x;
        const float gf = a1 + b4c.y + x4p[tt].y;
        const float go = a2 + b4c.z + x4p[tt].z;
        const float gm = a3 + b4c.w + x4p[tt].w;
        const float cn = sigm(gi) * tanhf(gm) + sigm(gf) * creg[tt];
        creg[tt] = cn;
        exCN[browA * 16 + hlA] = cn;
        exGO[tt][browA * 16 + hlA] = go;
      }
      __syncthreads();
      if (tid < 128) {   // pack + store c (16 rows x 8 col-pairs)
        const int rowe = tid >> 3, pr = tid & 7;
        const float2 cp = *(const float2*)(exCN + rowe * 16 + (pr << 1));
        union { unsigned u; f16 h2[2]; } pk;
        pk.h2[0] = (f16)cp.x; pk.h2[1] = (f16)cp.y;
        astore32(cb16 + (size_t)(m0t[tt] + rowe) * 512 + n0h + (pr << 1), pk.u);
      }
      __syncthreads();   // drains all waves' vmcnt -> c globally visible
      if (tid == 0)
        astorei(sl[tt] + grank, 2 * t + 1);
    }

#pragma unroll
    for (int tt = 0; tt < 2; ++tt) {
      // ===== phase B(tile tt): o-peephole GEMM + h write =====
      waitSlots(sl[tt], 2 * t + 1);
      // stage cT[tt] (new c; persists as next step's A operand)
#pragma unroll
      for (int j = 0; j < 4; ++j) {
        const int u = (j << 8) + tid;
        const int row = u >> 6, kg = u & 63;
        const f16* src = cb16 + (size_t)(m0t[tt] + row) * 512 + (kg << 3);
        union { f16x8 v; unsigned long long q[2]; } u2;
        u2.q[0] = aload64(src);
        u2.q[1] = aload64(src + 4);
        *(f16x8*)(&cT[tt][0] + row * 512 + ((kg >> 3) << 6) + (((kg & 7) ^ (row & 7)) << 3)) = u2.v;
      }
      __syncthreads();
      f32x4 accB = {};
      {
        const int ra = lane & 15;
#pragma unroll
        for (int j = 0; j < 4; ++j) {
          const int kc = w * 4 + j;
          const int kgl = ((kc & 1) << 2) + lk;
          const f16x8 af = *(const f16x8*)(&cT[tt][0] + ra * 512 + ((kc >> 1) << 6) +
                                           ((kgl ^ (ra & 7)) << 3));
          accB = __builtin_amdgcn_mfma_f32_16x16x32_f16(af, wO[j], accB, 0, 0, 0);
        }
      }
#pragma unroll
      for (int r4 = 0; r4 < 4; ++r4)
        ex2[w * 256 + ((lk << 2) + r4) * 16 + (lane & 15)] = accB[r4];
      __syncthreads();
      {
        const int ib = rowB * 16 + colB;
        const float sum = (ex2[ib] + ex2[256 + ib]) + (ex2[512 + ib] + ex2[768 + ib]);
        const int cg = n0h + colB;
        const float cn = (float)cT[tt][rowB * 512 + ((cg >> 6) << 6) +
                                       ((((cg >> 3) & 7) ^ (rowB & 7)) << 3) + (cg & 7)];
        const float hv = sigm(sum + exGO[tt][ib] + bco) * cn;
        const float hvo = __shfl_xor(hv, 1);
        if (!(tid & 1)) {
          union { unsigned u; f16 h2[2]; } pk;
          pk.h2[0] = (f16)hv; pk.h2[1] = (f16)hvo;
          astore32(h16 + (size_t)(m0t[tt] + rowB) * 512 + (cg & ~1), pk.u);
        }
        if (t == tlB[tt]) astore(lasth + (size_t)(m0t[tt] + rowB) * 512 + cg, hv);
      }
      __syncthreads();   // drains vmcnt -> h globally visible
      if (tid == 0)
        astorei(sl[tt] + grank, 2 * t + 2);
    }
  }

  // ===== final: out[b] = sigmoid(lasth . Wd + bd), one row per block =====
  waitSlots(sl[0], 2 * T_);
  waitSlots(sl[1], 2 * T_);
  if (w == 0) {
    const int b = pair * 32 + grank;
    float s = 0.f;
#pragma unroll
    for (int k = lane; k < 512; k += 64) s += aload(lasth + (size_t)b * 512 + k) * Wd[k];
#pragma unroll
    for (int off = 32; off > 0; off >>= 1) s += __shfl_down(s, off);
    if (lane == 0) out[b] = 1.0f / (1.0f + __expf(-(s + bd[0])));
  }
}

extern "C" void kernel_launch(void* const* d_in, const int* in_sizes, int n_in,
                              void* d_out, int out_size, void* d_ws, size_t ws_size,
                              hipStream_t stream) {
  const float* x   = (const float*)d_in[0];
  const int*   fix = (const int*)d_in[1];
  const float* Wx  = (const float*)d_in[2];
  const float* bx  = (const float*)d_in[3];
  const float* Wh  = (const float*)d_in[4];
  const float* bh  = (const float*)d_in[5];
  const float* Wc  = (const float*)d_in[6];
  const float* bc  = (const float*)d_in[7];
  const float* Wd  = (const float*)d_in[8];
  const float* bd  = (const float*)d_in[9];
  float* out = (float*)d_out;
  char* ws = (char*)d_ws;

  f16*   xg    = (f16*)(ws);                       // 14,680,064
  f16*   Wxh   = (f16*)(ws + 14680064);            //  8,388,608
  f16*   xproj = (f16*)(ws + 23068672);            // 14,680,064 (f16)
  f16*   Wbig  = (f16*)(ws + 52428800);            //  4,194,304
  f16*   Wc2h  = (f16*)(ws + 56623104);            //    524,288
  float* biasb = (float*)(ws + 57147392);          //      8,192
  float* bxp   = (float*)(ws + 57155584);          //      8,192
  f16*   h16   = (f16*)(ws + 57163776);            //    262,144
  f16*   cb16  = (f16*)(ws + 57425920);            //    262,144
  float* lasth = (float*)(ws + 57688064);          //    524,288
  int*   tlast = (int*)(ws + 58212352);            //      1,024
  int*   bar   = (int*)(ws + 58213376);            //      8,192

  hipMemsetAsync(h16, 0, 262144, stream);
  hipMemsetAsync(cb16, 0, 262144, stream);
  hipMemsetAsync(bar, 0, 8192, stream);

  k_prep_gather<<<1536, 256, 0, stream>>>(Wx, bx, Wh, Wc, bh, bc, fix, x,
                                          Wxh, bxp, Wbig, Wc2h, biasb, xg, tlast);
  k_gemm_big<<<dim3(16, 28), 256, 0, stream>>>(xg, Wxh, bxp, xproj);
  k_recur<<<NBLK, 256, 0, stream>>>(Wbig, Wc2h, biasb, bc, xproj, h16, cb16,
                                    lasth, tlast, Wd, bd, out, bar);
}